// Round 1
// baseline (340.347 us; speedup 1.0000x reference)
//
#include <hip/hip_runtime.h>

// 2-layer GAT forward, N nodes, K=16 neighbors (edges row-sorted, exactly 16/dst),
// feats 128 -> 64 -> 64, fp32 throughout.
//
// Layer decomposition:
//   K1: h = x @ W    (+ fused edge-score projections s1 = h.a[:64], s2 = h.a[64:])
//   K2: e_k = leaky(s1[dst] + s2[src_k]); att = softmax_16(e);
//       out[dst] = relu( sum_k att_k * h[src_k] + b )

template<int KDIM, int RPW>
__global__ __launch_bounds__(256) void gemm_score(
    const float* __restrict__ X, const float* __restrict__ W,
    const float* __restrict__ av, float* __restrict__ H,
    float* __restrict__ s1, float* __restrict__ s2, int n)
{
    constexpr int ROWS = RPW * 4;              // 4 waves/block
    __shared__ float Wl[KDIM * 64];
    __shared__ float Xl[ROWS * KDIM];
    const int tid = threadIdx.x;
    for (int i = tid; i < KDIM * 64; i += 256) Wl[i] = W[i];
    const int r0 = blockIdx.x * ROWS;
    for (int i = tid; i < ROWS * KDIM; i += 256) {
        int r = r0 + i / KDIM;
        Xl[i] = (r < n) ? X[(size_t)r0 * KDIM + i] : 0.0f;
    }
    __syncthreads();
    const int wave = tid >> 6, lane = tid & 63;
    const float a1v = av[lane], a2v = av[64 + lane];
    float acc[RPW];
#pragma unroll
    for (int rr = 0; rr < RPW; rr++) acc[rr] = 0.0f;
    const int rbase = wave * RPW;
#pragma unroll 4
    for (int k = 0; k < KDIM; k += 4) {
        // lane j reads column j of W for 4 consecutive k: bank = j%32, 2-way (free)
        float w0 = Wl[(k + 0) * 64 + lane];
        float w1 = Wl[(k + 1) * 64 + lane];
        float w2 = Wl[(k + 2) * 64 + lane];
        float w3 = Wl[(k + 3) * 64 + lane];
#pragma unroll
        for (int rr = 0; rr < RPW; rr++) {
            // wave-uniform b128 read of X (LDS broadcast)
            const float4 xv = *(const float4*)&Xl[(rbase + rr) * KDIM + k];
            acc[rr] = fmaf(xv.x, w0, acc[rr]);
            acc[rr] = fmaf(xv.y, w1, acc[rr]);
            acc[rr] = fmaf(xv.z, w2, acc[rr]);
            acc[rr] = fmaf(xv.w, w3, acc[rr]);
        }
    }
#pragma unroll
    for (int rr = 0; rr < RPW; rr++) {
        const int r = r0 + rbase + rr;
        if (r < n) {
            H[(size_t)r * 64 + lane] = acc[rr];
            float p1 = acc[rr] * a1v;
            float p2 = acc[rr] * a2v;
#pragma unroll
            for (int m = 1; m < 64; m <<= 1) {
                p1 += __shfl_xor(p1, m, 64);
                p2 += __shfl_xor(p2, m, 64);
            }
            if (lane == 0) { s1[r] = p1; s2[r] = p2; }
        }
    }
}

// One wave per destination node; lane = output feature (64 feats = 64 lanes).
__global__ __launch_bounds__(256) void attn_agg(
    const float* __restrict__ H, const float* __restrict__ s1,
    const float* __restrict__ s2, const int* __restrict__ col,
    const float* __restrict__ bias, float* __restrict__ out, int n)
{
    const int lane = threadIdx.x & 63;
    const int dst = blockIdx.x * 4 + (threadIdx.x >> 6);
    if (dst >= n) return;

    // every 16-lane group computes the same 16 edge scores (replicated, cheap)
    const int c = col[dst * 16 + (lane & 15)];
    float e = s1[dst] + s2[c];
    e = (e > 0.0f) ? e : 0.2f * e;                      // leaky_relu slope 0.2
    float m = e;
#pragma unroll
    for (int msk = 1; msk < 16; msk <<= 1) m = fmaxf(m, __shfl_xor(m, msk, 64));
    float p = __expf(e - m);
    float s = p;
#pragma unroll
    for (int msk = 1; msk < 16; msk <<= 1) s += __shfl_xor(s, msk, 64);
    const float att = p / s;

    int   srck[16];
    float attk[16];
#pragma unroll
    for (int k = 0; k < 16; k++) {
        srck[k] = __shfl(c,   k, 64);
        attk[k] = __shfl(att, k, 64);
    }
    // 16 independent coalesced 256B row-gathers (latency-hidden by occupancy)
    float hv[16];
#pragma unroll
    for (int k = 0; k < 16; k++) hv[k] = H[(size_t)srck[k] * 64 + lane];
    float acc = 0.0f;
#pragma unroll
    for (int k = 0; k < 16; k++) acc = fmaf(attk[k], hv[k], acc);

    float v = acc + bias[lane];
    out[(size_t)dst * 64 + lane] = fmaxf(v, 0.0f);      // relu (both layers)
}

extern "C" void kernel_launch(void* const* d_in, const int* in_sizes, int n_in,
                              void* d_out, int out_size, void* d_ws, size_t ws_size,
                              hipStream_t stream)
{
    const float* x        = (const float*)d_in[0];
    const int*   edge_col = (const int*)  d_in[2];
    const float* W1       = (const float*)d_in[3];
    const float* a1       = (const float*)d_in[4];
    const float* b1       = (const float*)d_in[5];
    const float* W2       = (const float*)d_in[6];
    const float* a2       = (const float*)d_in[7];
    const float* b2       = (const float*)d_in[8];
    const int n = in_sizes[0] / 128;     // 100000

    float* h  = (float*)d_ws;            // n*64
    float* xm = h  + (size_t)n * 64;     // n*64
    float* s1 = xm + (size_t)n * 64;     // n
    float* s2 = s1 + n;                  // n

    dim3 blk(256);
    const int gemm_blocks = (n + 31) / 32;   // 32 rows/block
    const int agg_blocks  = (n + 3) / 4;     // 4 nodes/block

    // layer 1
    gemm_score<128, 8><<<gemm_blocks, blk, 0, stream>>>(x, W1, a1, h, s1, s2, n);
    attn_agg<<<agg_blocks, blk, 0, stream>>>(h, s1, s2, edge_col, b1, xm, n);
    // layer 2
    gemm_score<64, 8><<<gemm_blocks, blk, 0, stream>>>(xm, W2, a2, h, s1, s2, n);
    attn_agg<<<agg_blocks, blk, 0, stream>>>(h, s1, s2, edge_col, b2, (float*)d_out, n);
}

// Round 2
// 241.129 us; speedup vs baseline: 1.4115x; 1.4115x over previous
//
#include <hip/hip_runtime.h>

// 2-layer GAT forward, N nodes, K=16 neighbors (row-sorted, exactly 16/dst),
// feats 128 -> 64 -> 64, fp32.
//
// GEMM is done on matrix cores via bf16 split emulation:
//   x = xh + xl, W = Wh + Wl (bf16);  h ~= xh*Wh + xh*Wl + xl*Wh  (fp32 acc)
// -> ~2^-16 relative error, way below the 5.7e-3 harness threshold.

typedef __attribute__((ext_vector_type(8))) short bf16x8;
typedef __attribute__((ext_vector_type(4))) float floatx4;

__device__ inline unsigned short f2bf(float x) {
    union { float f; unsigned u; } v; v.f = x;
    unsigned r = v.u + 0x7fff + ((v.u >> 16) & 1);   // round-nearest-even
    return (unsigned short)(r >> 16);
}
__device__ inline float bf2f(unsigned short b) {
    union { float f; unsigned u; } v; v.u = ((unsigned)b) << 16;
    return v.f;
}
__device__ inline void split_bf(float x, unsigned short& h, unsigned short& l) {
    h = f2bf(x);
    l = f2bf(x - bf2f(h));
}

// ---- one-time W -> MFMA-B-fragment packing (hi/lo bf16) --------------------
// B-frag layout for mfma_f32_16x16x32_bf16: lane holds B[k=kt*32+(lane>>4)*8+j][n=nt*16+(lane&15)]
template<int KD>
__device__ void pack_one(const float* __restrict__ W,
                         unsigned short* __restrict__ hi,
                         unsigned short* __restrict__ lo) {
    constexpr int NF = (KD / 32) * 4 * 64;
    for (int f = threadIdx.x; f < NF; f += 256) {
        const int ln = f & 63, ntk = f >> 6;
        const int kt = ntk >> 2, nt = ntk & 3;
        const int kbase = kt * 32 + (ln >> 4) * 8;
        const int c = nt * 16 + (ln & 15);
#pragma unroll
        for (int j = 0; j < 8; j++) {
            unsigned short h, l;
            split_bf(W[(kbase + j) * 64 + c], h, l);
            hi[f * 8 + j] = h;
            lo[f * 8 + j] = l;
        }
    }
}
__global__ __launch_bounds__(256) void pack_w(
    const float* __restrict__ W1, const float* __restrict__ W2,
    unsigned short* B1hi, unsigned short* B1lo,
    unsigned short* B2hi, unsigned short* B2lo) {
    if (blockIdx.x == 0) pack_one<128>(W1, B1hi, B1lo);
    else                 pack_one<64>(W2, B2hi, B2lo);
}

// ---- h = X @ W (MFMA), fused s1 = h.a[:64], s2 = h.a[64:] ------------------
template<int KD, int ROWIT>
__global__ __launch_bounds__(256) void gemm_score_mfma(
    const float* __restrict__ X,
    const unsigned short* __restrict__ Bhig, const unsigned short* __restrict__ Blog,
    const float* __restrict__ av, float* __restrict__ H,
    float* __restrict__ s1, float* __restrict__ s2, int n)
{
    constexpr int NKT = KD / 32;
    constexpr int NF = NKT * 4 * 64;
    __shared__ bf16x8 Bhi[NF];
    __shared__ bf16x8 Blo[NF];
    {   // coalesced 16B/thread copy of pre-packed fragments into LDS
        const uint4* sh = (const uint4*)Bhig;
        const uint4* sl = (const uint4*)Blog;
        uint4* dh = (uint4*)Bhi;
        uint4* dl = (uint4*)Blo;
        for (int i = threadIdx.x; i < NF; i += 256) { dh[i] = sh[i]; dl[i] = sl[i]; }
    }
    __syncthreads();

    const int tid = threadIdx.x;
    const int wave = tid >> 6, lane = tid & 63;
    const int quad = lane >> 4, l15 = lane & 15;
    float a1c[4], a2c[4];
#pragma unroll
    for (int nt = 0; nt < 4; nt++) {
        a1c[nt] = av[nt * 16 + l15];
        a2c[nt] = av[64 + nt * 16 + l15];
    }

    for (int it = 0; it < ROWIT; it++) {
        const int r0 = (blockIdx.x * ROWIT + it) * 64 + wave * 16;
        if (r0 >= n) break;                         // wave-uniform
        int ra = r0 + l15; if (ra > n - 1) ra = n - 1;

        // A fragments: lane holds A[m=l15][k=kt*32+quad*8+j], split hi/lo
        bf16x8 Ahi[NKT], Alo[NKT];
#pragma unroll
        for (int kt = 0; kt < NKT; kt++) {
            const float4 x0 = *(const float4*)&X[(size_t)ra * KD + kt * 32 + quad * 8];
            const float4 x1 = *(const float4*)&X[(size_t)ra * KD + kt * 32 + quad * 8 + 4];
            const float xs[8] = {x0.x, x0.y, x0.z, x0.w, x1.x, x1.y, x1.z, x1.w};
#pragma unroll
            for (int j = 0; j < 8; j++) {
                unsigned short h, l;
                split_bf(xs[j], h, l);
                Ahi[kt][j] = (short)h;
                Alo[kt][j] = (short)l;
            }
        }

        floatx4 acc[4] = {{0,0,0,0},{0,0,0,0},{0,0,0,0},{0,0,0,0}};
#pragma unroll
        for (int kt = 0; kt < NKT; kt++) {
#pragma unroll
            for (int nt = 0; nt < 4; nt++) {
                const int f = (kt * 4 + nt) * 64 + lane;
                const bf16x8 bh = Bhi[f];
                const bf16x8 bl = Blo[f];
                acc[nt] = __builtin_amdgcn_mfma_f32_16x16x32_bf16(Ahi[kt], bh, acc[nt], 0, 0, 0);
                acc[nt] = __builtin_amdgcn_mfma_f32_16x16x32_bf16(Ahi[kt], bl, acc[nt], 0, 0, 0);
                acc[nt] = __builtin_amdgcn_mfma_f32_16x16x32_bf16(Alo[kt], bh, acc[nt], 0, 0, 0);
            }
        }

        // epilogue: C layout col=l15(+16*nt), row=quad*4+reg
        float p1[4] = {0,0,0,0}, p2[4] = {0,0,0,0};
#pragma unroll
        for (int nt = 0; nt < 4; nt++) {
#pragma unroll
            for (int reg = 0; reg < 4; reg++) {
                const int r = r0 + quad * 4 + reg;
                if (r < n) H[(size_t)r * 64 + nt * 16 + l15] = acc[nt][reg];
                p1[reg] = fmaf(acc[nt][reg], a1c[nt], p1[reg]);
                p2[reg] = fmaf(acc[nt][reg], a2c[nt], p2[reg]);
            }
        }
#pragma unroll
        for (int m = 1; m < 16; m <<= 1) {
#pragma unroll
            for (int reg = 0; reg < 4; reg++) {
                p1[reg] += __shfl_xor(p1[reg], m, 64);
                p2[reg] += __shfl_xor(p2[reg], m, 64);
            }
        }
        if (l15 == 0) {
#pragma unroll
            for (int reg = 0; reg < 4; reg++) {
                const int r = r0 + quad * 4 + reg;
                if (r < n) { s1[r] = p1[reg]; s2[r] = p2[reg]; }
            }
        }
    }
}

// ---- attention + aggregate: one wave per dst node, lane = feature ----------
__global__ __launch_bounds__(256) void attn_agg(
    const float* __restrict__ H, const float* __restrict__ s1,
    const float* __restrict__ s2, const int* __restrict__ col,
    const float* __restrict__ bias, float* __restrict__ out, int n)
{
    const int lane = threadIdx.x & 63;
    const int dst = blockIdx.x * 4 + (threadIdx.x >> 6);
    if (dst >= n) return;

    const int c = col[dst * 16 + (lane & 15)];
    float e = s1[dst] + s2[c];
    e = (e > 0.0f) ? e : 0.2f * e;                       // leaky_relu 0.2
    float m = e;
#pragma unroll
    for (int msk = 1; msk < 16; msk <<= 1) m = fmaxf(m, __shfl_xor(m, msk, 64));
    float p = __expf(e - m);
    float s = p;
#pragma unroll
    for (int msk = 1; msk < 16; msk <<= 1) s += __shfl_xor(s, msk, 64);
    const float att = p / s;

    int   srck[16];
    float attk[16];
#pragma unroll
    for (int k = 0; k < 16; k++) {
        srck[k] = __shfl(c,   k, 64);
        attk[k] = __shfl(att, k, 64);
    }
    float hv[16];
#pragma unroll
    for (int k = 0; k < 16; k++) hv[k] = H[(size_t)srck[k] * 64 + lane];
    float acc = 0.0f;
#pragma unroll
    for (int k = 0; k < 16; k++) acc = fmaf(attk[k], hv[k], acc);

    const float v = acc + bias[lane];
    out[(size_t)dst * 64 + lane] = fmaxf(v, 0.0f);       // relu
}

extern "C" void kernel_launch(void* const* d_in, const int* in_sizes, int n_in,
                              void* d_out, int out_size, void* d_ws, size_t ws_size,
                              hipStream_t stream)
{
    const float* x        = (const float*)d_in[0];
    const int*   edge_col = (const int*)  d_in[2];
    const float* W1       = (const float*)d_in[3];
    const float* a1       = (const float*)d_in[4];
    const float* b1       = (const float*)d_in[5];
    const float* W2       = (const float*)d_in[6];
    const float* a2       = (const float*)d_in[7];
    const float* b2       = (const float*)d_in[8];
    const int n = in_sizes[0] / 128;     // 100000

    float* h  = (float*)d_ws;            // n*64
    float* xm = h  + (size_t)n * 64;     // n*64
    float* s1 = xm + (size_t)n * 64;     // n
    float* s2 = s1 + n;                  // n
    unsigned short* B1hi = (unsigned short*)(s2 + n);   // 4*4*64*8 = 8192
    unsigned short* B1lo = B1hi + 8192;
    unsigned short* B2hi = B1lo + 8192;                 // 2*4*64*8 = 4096
    unsigned short* B2lo = B2hi + 4096;

    dim3 blk(256);
    constexpr int ROWIT = 2;
    const int gemm_blocks = (n + ROWIT * 64 - 1) / (ROWIT * 64);
    const int agg_blocks  = (n + 3) / 4;

    pack_w<<<2, blk, 0, stream>>>(W1, W2, B1hi, B1lo, B2hi, B2lo);
    // layer 1
    gemm_score_mfma<128, ROWIT><<<gemm_blocks, blk, 0, stream>>>(x, B1hi, B1lo, a1, h, s1, s2, n);
    attn_agg<<<agg_blocks, blk, 0, stream>>>(h, s1, s2, edge_col, b1, xm, n);
    // layer 2
    gemm_score_mfma<64, ROWIT><<<gemm_blocks, blk, 0, stream>>>(xm, B2hi, B2lo, a2, h, s1, s2, n);
    attn_agg<<<agg_blocks, blk, 0, stream>>>(h, s1, s2, edge_col, b2, (float*)d_out, n);
}

// Round 3
// 218.748 us; speedup vs baseline: 1.5559x; 1.1023x over previous
//
#include <hip/hip_runtime.h>

// 2-layer GAT forward, N nodes, K=16 neighbors (row-sorted, exactly 16/dst),
// feats 128 -> 64 -> 64, fp32 in/out.
//
// GEMM on matrix cores via bf16 split emulation with TRUNCATION split:
//   xh = trunc16(x), xl = trunc16(x - xh);  h ~= xh*Wh + xh*Wl + xl*Wh (fp32 acc)
//   error ~2^-16 relative (lo corrects hi; dropped xl*wl term is 2^-16).
// H is stored fp16 (2^-11 rel err) to halve the random-gather traffic in attn.

typedef __attribute__((ext_vector_type(8))) short bf16x8;
typedef __attribute__((ext_vector_type(4))) float floatx4;

__device__ inline unsigned short f2bf(float x) {
    union { float f; unsigned u; } v; v.f = x;
    unsigned r = v.u + 0x7fff + ((v.u >> 16) & 1);   // RNE
    return (unsigned short)(r >> 16);
}
__device__ inline float bf2f(unsigned short b) {
    union { float f; unsigned u; } v; v.u = ((unsigned)b) << 16;
    return v.f;
}
__device__ inline void split_bf(float x, unsigned short& h, unsigned short& l) {
    h = f2bf(x);
    l = f2bf(x - bf2f(h));
}
__device__ inline float ubitf(unsigned u) { union { unsigned u; float f; } v; v.u = u; return v.f; }
__device__ inline unsigned fbitu(float f) { union { float f; unsigned u; } v; v.f = f; return v.u; }

// ---- one-time W -> MFMA-B-fragment packing (hi/lo bf16), parallel ----------
// B-frag layout (16x16x32 bf16): lane holds B[k=kt*32+(lane>>4)*8+j][n=nt*16+(lane&15)]
// frag id f = (kt*4+nt)*64 + lane;  W1: 4096 frags, W2: 2048 frags.
__global__ __launch_bounds__(256) void pack_w(
    const float* __restrict__ W1, const float* __restrict__ W2,
    unsigned short* __restrict__ B1hi, unsigned short* __restrict__ B1lo,
    unsigned short* __restrict__ B2hi, unsigned short* __restrict__ B2lo)
{
    int f = blockIdx.x * 256 + threadIdx.x;       // 24 blocks -> 6144 threads
    const float* W; unsigned short *hi, *lo;
    if (f < 4096) { W = W1; hi = B1hi; lo = B1lo; }
    else          { f -= 4096; W = W2; hi = B2hi; lo = B2lo; }
    const int ln = f & 63, ntk = f >> 6;
    const int kt = ntk >> 2, nt = ntk & 3;
    const int kbase = kt * 32 + (ln >> 4) * 8;
    const int c = nt * 16 + (ln & 15);
    unsigned short hs[8], ls[8];
#pragma unroll
    for (int j = 0; j < 8; j++) split_bf(W[(kbase + j) * 64 + c], hs[j], ls[j]);
    *(uint4*)&hi[f * 8] = *(const uint4*)hs;      // 16B vector stores
    *(uint4*)&lo[f * 8] = *(const uint4*)ls;
}

// ---- h = X @ W (MFMA), fused s1 = h.a[:64], s2 = h.a[64:]; H stored fp16 ---
template<int KD, int ROWIT>
__global__ __launch_bounds__(256) void gemm_score_mfma(
    const float* __restrict__ X,
    const unsigned short* __restrict__ Bhig, const unsigned short* __restrict__ Blog,
    const float* __restrict__ av, _Float16* __restrict__ H,
    float* __restrict__ s1, float* __restrict__ s2, int n)
{
    constexpr int NKT = KD / 32;
    constexpr int NF = NKT * 4 * 64;
    __shared__ bf16x8 Bhi[NF];
    __shared__ bf16x8 Blo[NF];
    {
        const uint4* sh = (const uint4*)Bhig;
        const uint4* sl = (const uint4*)Blog;
        uint4* dh = (uint4*)Bhi;
        uint4* dl = (uint4*)Blo;
        for (int i = threadIdx.x; i < NF; i += 256) { dh[i] = sh[i]; dl[i] = sl[i]; }
    }
    __syncthreads();

    const int tid = threadIdx.x;
    const int wave = tid >> 6, lane = tid & 63;
    const int quad = lane >> 4, l15 = lane & 15;
    float a1c[4], a2c[4];
#pragma unroll
    for (int nt = 0; nt < 4; nt++) {
        a1c[nt] = av[nt * 16 + l15];
        a2c[nt] = av[64 + nt * 16 + l15];
    }

    for (int it = 0; it < ROWIT; it++) {
        const int r0 = (blockIdx.x * ROWIT + it) * 64 + wave * 16;
        if (r0 >= n) break;                          // wave-uniform
        int ra = r0 + l15; if (ra > n - 1) ra = n - 1;

        // A fragments: lane holds A[m=l15][k=kt*32+quad*8+j], truncation hi/lo.
        bf16x8 Ahi[NKT], Alo[NKT];
#pragma unroll
        for (int kt = 0; kt < NKT; kt++) {
            const uint4 q0 = *(const uint4*)&X[(size_t)ra * KD + kt * 32 + quad * 8];
            const uint4 q1 = *(const uint4*)&X[(size_t)ra * KD + kt * 32 + quad * 8 + 4];
            const unsigned u[8] = {q0.x, q0.y, q0.z, q0.w, q1.x, q1.y, q1.z, q1.w};
            union { bf16x8 v; unsigned w[4]; } ah, al;
#pragma unroll
            for (int i = 0; i < 4; i++) {
                const unsigned a = u[2 * i], b = u[2 * i + 1];
                ah.w[i] = __builtin_amdgcn_perm(b, a, 0x07060302);   // {hi16(b),hi16(a)}
                const float ra0 = ubitf(a) - ubitf(a & 0xffff0000u);
                const float rb0 = ubitf(b) - ubitf(b & 0xffff0000u);
                al.w[i] = __builtin_amdgcn_perm(fbitu(rb0), fbitu(ra0), 0x07060302);
            }
            Ahi[kt] = ah.v;
            Alo[kt] = al.v;
        }

        floatx4 acc[4] = {{0,0,0,0},{0,0,0,0},{0,0,0,0},{0,0,0,0}};
#pragma unroll
        for (int kt = 0; kt < NKT; kt++) {
#pragma unroll
            for (int nt = 0; nt < 4; nt++) {
                const int f = (kt * 4 + nt) * 64 + lane;
                const bf16x8 bh = Bhi[f];
                const bf16x8 bl = Blo[f];
                acc[nt] = __builtin_amdgcn_mfma_f32_16x16x32_bf16(Ahi[kt], bh, acc[nt], 0, 0, 0);
                acc[nt] = __builtin_amdgcn_mfma_f32_16x16x32_bf16(Ahi[kt], bl, acc[nt], 0, 0, 0);
                acc[nt] = __builtin_amdgcn_mfma_f32_16x16x32_bf16(Alo[kt], bh, acc[nt], 0, 0, 0);
            }
        }

        // epilogue: C layout col=nt*16+l15, row=quad*4+reg
        float p1[4] = {0,0,0,0}, p2[4] = {0,0,0,0};
#pragma unroll
        for (int nt = 0; nt < 4; nt++) {
#pragma unroll
            for (int reg = 0; reg < 4; reg++) {
                const int r = r0 + quad * 4 + reg;
                if (r < n) H[(size_t)r * 64 + nt * 16 + l15] = (_Float16)acc[nt][reg];
                p1[reg] = fmaf(acc[nt][reg], a1c[nt], p1[reg]);
                p2[reg] = fmaf(acc[nt][reg], a2c[nt], p2[reg]);
            }
        }
#pragma unroll
        for (int m = 1; m < 16; m <<= 1) {
#pragma unroll
            for (int reg = 0; reg < 4; reg++) {
                p1[reg] += __shfl_xor(p1[reg], m, 64);
                p2[reg] += __shfl_xor(p2[reg], m, 64);
            }
        }
        if (l15 == 0) {
#pragma unroll
            for (int reg = 0; reg < 4; reg++) {
                const int r = r0 + quad * 4 + reg;
                if (r < n) { s1[r] = p1[reg]; s2[r] = p2[reg]; }
            }
        }
    }
}

// ---- attention + aggregate: one wave per dst node, lane = feature ----------
__global__ __launch_bounds__(256) void attn_agg(
    const _Float16* __restrict__ H, const float* __restrict__ s1,
    const float* __restrict__ s2, const int* __restrict__ col,
    const float* __restrict__ bias, float* __restrict__ out, int n)
{
    const int lane = threadIdx.x & 63;
    const int dst = blockIdx.x * 4 + (threadIdx.x >> 6);
    if (dst >= n) return;

    const int c = col[dst * 16 + (lane & 15)];
    float e = s1[dst] + s2[c];
    e = (e > 0.0f) ? e : 0.2f * e;                       // leaky_relu 0.2
    float m = e;
#pragma unroll
    for (int msk = 1; msk < 16; msk <<= 1) m = fmaxf(m, __shfl_xor(m, msk, 64));
    float p = __expf(e - m);
    float s = p;
#pragma unroll
    for (int msk = 1; msk < 16; msk <<= 1) s += __shfl_xor(s, msk, 64);
    const float att = p / s;

    int   srck[16];
    float attk[16];
#pragma unroll
    for (int k = 0; k < 16; k++) {
        srck[k] = __shfl(c,   k, 64);
        attk[k] = __shfl(att, k, 64);
    }
    float hv[16];
#pragma unroll
    for (int k = 0; k < 16; k++) hv[k] = (float)H[(size_t)srck[k] * 64 + lane];
    float acc = 0.0f;
#pragma unroll
    for (int k = 0; k < 16; k++) acc = fmaf(attk[k], hv[k], acc);

    const float v = acc + bias[lane];
    out[(size_t)dst * 64 + lane] = fmaxf(v, 0.0f);       // relu
}

extern "C" void kernel_launch(void* const* d_in, const int* in_sizes, int n_in,
                              void* d_out, int out_size, void* d_ws, size_t ws_size,
                              hipStream_t stream)
{
    const float* x        = (const float*)d_in[0];
    const int*   edge_col = (const int*)  d_in[2];
    const float* W1       = (const float*)d_in[3];
    const float* a1       = (const float*)d_in[4];
    const float* b1       = (const float*)d_in[5];
    const float* W2       = (const float*)d_in[6];
    const float* a2       = (const float*)d_in[7];
    const float* b2       = (const float*)d_in[8];
    const int n = in_sizes[0] / 128;     // 100000

    // workspace layout
    _Float16* h  = (_Float16*)d_ws;                     // n*64 fp16
    float* xm = (float*)(h + (size_t)n * 64);           // n*64 fp32
    float* s1 = xm + (size_t)n * 64;                    // n
    float* s2 = s1 + n;                                 // n
    unsigned short* B1hi = (unsigned short*)(s2 + n);   // 4096*8
    unsigned short* B1lo = B1hi + 32768;
    unsigned short* B2hi = B1lo + 32768;                // 2048*8
    unsigned short* B2lo = B2hi + 16384;

    dim3 blk(256);
    constexpr int ROWIT = 2;
    const int gemm_blocks = (n + ROWIT * 64 - 1) / (ROWIT * 64);
    const int agg_blocks  = (n + 3) / 4;

    pack_w<<<24, blk, 0, stream>>>(W1, W2, B1hi, B1lo, B2hi, B2lo);
    // layer 1
    gemm_score_mfma<128, ROWIT><<<gemm_blocks, blk, 0, stream>>>(x, B1hi, B1lo, a1, h, s1, s2, n);
    attn_agg<<<agg_blocks, blk, 0, stream>>>(h, s1, s2, edge_col, b1, xm, n);
    // layer 2
    gemm_score_mfma<64, ROWIT><<<gemm_blocks, blk, 0, stream>>>(xm, B2hi, B2lo, a2, h, s1, s2, n);
    attn_agg<<<agg_blocks, blk, 0, stream>>>(h, s1, s2, edge_col, b2, (float*)d_out, n);
}

// Round 4
// 190.380 us; speedup vs baseline: 1.7877x; 1.1490x over previous
//
#include <hip/hip_runtime.h>

// 2-layer GAT forward, N nodes, K=16 neighbors (row-sorted, exactly 16/dst),
// feats 128 -> 64 -> 64, fp32 in/out.
//
// GEMM on matrix cores via bf16 truncation-split emulation:
//   xh = trunc16(x), xl = trunc16(x - xh);  h ~= xh*Wh + xh*Wl + xl*Wh (fp32 acc)
// H stored fp16 (2^-11 rel) to halve random-gather traffic in attn.
// attn: 4 nodes per wave (16 lanes/node), 512B per gather instruction.

typedef __attribute__((ext_vector_type(8))) short bf16x8;
typedef __attribute__((ext_vector_type(4))) float floatx4;
typedef __attribute__((ext_vector_type(4))) _Float16 f16x4;

__device__ inline float ubitf(unsigned u) { union { unsigned u; float f; } v; v.u = u; return v.f; }
__device__ inline unsigned fbitu(float f) { union { float f; unsigned u; } v; v.f = f; return v.u; }

// pack two fp32 into bf16 pair {lo16=hi16(a), hi16=hi16(b)} via v_perm
__device__ inline unsigned pack_hi16(unsigned a, unsigned b) {
    return __builtin_amdgcn_perm(b, a, 0x07060302);
}

// ---- h = X @ W (MFMA) + fused s1 = h.a[:64], s2 = h.a[64:]; H out fp16 -----
// Per block: 256 threads = 4 waves, each wave 48 rows (3 MFMA row-tiles).
// W (KDx64) split+packed into LDS B-fragments in the preamble (no extra kernel).
template<int KD>
__global__ __launch_bounds__(256, 2) void gemm_score_mfma(
    const float* __restrict__ X, const float* __restrict__ W,
    const float* __restrict__ av, _Float16* __restrict__ H,
    float* __restrict__ s1, float* __restrict__ s2, int n)
{
    constexpr int NKT = KD / 32;
    constexpr int NF = NKT * 4 * 64;          // B fragments (16B each)
    __shared__ bf16x8 Bhi[NF];
    __shared__ bf16x8 Blo[NF];
    const int tid = threadIdx.x;

    // ---- W -> split bf16 MFMA B-fragments in LDS ----
    // frag f=(kt*4+nt)*64+lane holds B[k=kt*32+(lane>>4)*8+j][c=nt*16+(lane&15)]
    for (int f = tid; f < NF; f += 256) {
        const int ln = f & 63, ntk = f >> 6;
        const int kt = ntk >> 2, nt = ntk & 3;
        const int kbase = kt * 32 + (ln >> 4) * 8;
        const int ccol = nt * 16 + (ln & 15);
        union { bf16x8 v; unsigned w[4]; } hh, ll;
#pragma unroll
        for (int i = 0; i < 4; i++) {
            const unsigned ua = fbitu(W[(kbase + 2 * i) * 64 + ccol]);
            const unsigned ub = fbitu(W[(kbase + 2 * i + 1) * 64 + ccol]);
            hh.w[i] = pack_hi16(ua, ub);
            const float ra = ubitf(ua) - ubitf(ua & 0xffff0000u);
            const float rb = ubitf(ub) - ubitf(ub & 0xffff0000u);
            ll.w[i] = pack_hi16(fbitu(ra), fbitu(rb));
        }
        Bhi[f] = hh.v; Blo[f] = ll.v;
    }
    __syncthreads();

    const int wave = tid >> 6, lane = tid & 63;
    const int quad = lane >> 4, l15 = lane & 15;
    const int r0 = blockIdx.x * 192 + wave * 48;

    float a1c[4], a2c[4];
#pragma unroll
    for (int nt = 0; nt < 4; nt++) {
        a1c[nt] = av[nt * 16 + l15];
        a2c[nt] = av[64 + nt * 16 + l15];
    }

    // ---- prefetch ALL raw X for this wave's 48 rows (max memory-level par.) --
    uint4 raw[NKT][3][2];
#pragma unroll
    for (int rb = 0; rb < 3; rb++) {
        int ra = r0 + rb * 16 + l15; if (ra > n - 1) ra = n - 1;
        const float* xp = &X[(size_t)ra * KD + quad * 8];
#pragma unroll
        for (int kt = 0; kt < NKT; kt++) {
            raw[kt][rb][0] = *(const uint4*)(xp + kt * 32);
            raw[kt][rb][1] = *(const uint4*)(xp + kt * 32 + 4);
        }
    }

    floatx4 acc[4][3];
#pragma unroll
    for (int nt = 0; nt < 4; nt++)
#pragma unroll
        for (int rb = 0; rb < 3; rb++) acc[nt][rb] = (floatx4){0, 0, 0, 0};

#pragma unroll
    for (int kt = 0; kt < NKT; kt++) {
        bf16x8 Ahi[3], Alo[3];
#pragma unroll
        for (int rb = 0; rb < 3; rb++) {
            const unsigned u[8] = {raw[kt][rb][0].x, raw[kt][rb][0].y,
                                   raw[kt][rb][0].z, raw[kt][rb][0].w,
                                   raw[kt][rb][1].x, raw[kt][rb][1].y,
                                   raw[kt][rb][1].z, raw[kt][rb][1].w};
            union { bf16x8 v; unsigned w[4]; } ah, al;
#pragma unroll
            for (int i = 0; i < 4; i++) {
                const unsigned a = u[2 * i], b = u[2 * i + 1];
                ah.w[i] = pack_hi16(a, b);
                const float ra = ubitf(a) - ubitf(a & 0xffff0000u);
                const float rb2 = ubitf(b) - ubitf(b & 0xffff0000u);
                al.w[i] = pack_hi16(fbitu(ra), fbitu(rb2));
            }
            Ahi[rb] = ah.v; Alo[rb] = al.v;
        }
#pragma unroll
        for (int nt = 0; nt < 4; nt++) {
            const bf16x8 bh = Bhi[(kt * 4 + nt) * 64 + lane];
            const bf16x8 bl = Blo[(kt * 4 + nt) * 64 + lane];
#pragma unroll
            for (int rb = 0; rb < 3; rb++) {
                acc[nt][rb] = __builtin_amdgcn_mfma_f32_16x16x32_bf16(Ahi[rb], bh, acc[nt][rb], 0, 0, 0);
                acc[nt][rb] = __builtin_amdgcn_mfma_f32_16x16x32_bf16(Ahi[rb], bl, acc[nt][rb], 0, 0, 0);
                acc[nt][rb] = __builtin_amdgcn_mfma_f32_16x16x32_bf16(Alo[rb], bh, acc[nt][rb], 0, 0, 0);
            }
        }
    }

    // ---- epilogue: C layout col=nt*16+l15, row=quad*4+reg ----
#pragma unroll
    for (int rb = 0; rb < 3; rb++) {
        float p1[4] = {0, 0, 0, 0}, p2[4] = {0, 0, 0, 0};
#pragma unroll
        for (int nt = 0; nt < 4; nt++) {
#pragma unroll
            for (int reg = 0; reg < 4; reg++) {
                const int r = r0 + rb * 16 + quad * 4 + reg;
                if (r < n) H[(size_t)r * 64 + nt * 16 + l15] = (_Float16)acc[nt][rb][reg];
                p1[reg] = fmaf(acc[nt][rb][reg], a1c[nt], p1[reg]);
                p2[reg] = fmaf(acc[nt][rb][reg], a2c[nt], p2[reg]);
            }
        }
#pragma unroll
        for (int m = 1; m < 16; m <<= 1) {
#pragma unroll
            for (int reg = 0; reg < 4; reg++) {
                p1[reg] += __shfl_xor(p1[reg], m, 64);
                p2[reg] += __shfl_xor(p2[reg], m, 64);
            }
        }
        if (l15 == 0) {
#pragma unroll
            for (int reg = 0; reg < 4; reg++) {
                const int r = r0 + rb * 16 + quad * 4 + reg;
                if (r < n) { s1[r] = p1[reg]; s2[r] = p2[reg]; }
            }
        }
    }
}

// ---- attention + aggregate: 4 nodes per wave, 16 lanes per node ------------
// lane = g*16+j: node group g (0..3), edge/feature index j (0..15).
// Each lane owns 4 output features (j*4..j*4+3); gathers are f16x4 (8B/lane),
// so one gather instruction moves 4 rows x 128B = 512B.
__global__ __launch_bounds__(512) void attn_agg(
    const _Float16* __restrict__ H, const float* __restrict__ s1,
    const float* __restrict__ s2, const int* __restrict__ col,
    const float* __restrict__ bias, float* __restrict__ out, int n)
{
    const int lane = threadIdx.x & 63;
    const int wv = threadIdx.x >> 6;                 // 0..7
    const int j = lane & 15;
    const int dst = blockIdx.x * 32 + wv * 4 + (lane >> 4);
    if (dst >= n) return;

    const int c = col[dst * 16 + j];                 // coalesced 256B/wave
    float e = s1[dst] + s2[c];
    e = (e > 0.0f) ? e : 0.2f * e;                   // leaky_relu 0.2
    float m = e;
#pragma unroll
    for (int mk = 1; mk < 16; mk <<= 1) m = fmaxf(m, __shfl_xor(m, mk, 64));
    float p = __expf(e - m);
    float s = p;
#pragma unroll
    for (int mk = 1; mk < 16; mk <<= 1) s += __shfl_xor(s, mk, 64);
    const float att = p / s;

    // broadcast (src,att) of each of the group's 16 edges to all 16 lanes
    const int bbase = (lane & 48) << 2;              // group-base byte index
    int srck[16]; float attk[16];
#pragma unroll
    for (int k = 0; k < 16; k++) {
        const int bidx = bbase + (k << 2);
        srck[k] = __builtin_amdgcn_ds_bpermute(bidx, c);
        attk[k] = ubitf((unsigned)__builtin_amdgcn_ds_bpermute(bidx, (int)fbitu(att)));
    }
    f16x4 hv[16];
#pragma unroll
    for (int k = 0; k < 16; k++)
        hv[k] = *(const f16x4*)&H[(size_t)srck[k] * 64 + j * 4];

    float a0 = 0, a1 = 0, a2 = 0, a3 = 0;
#pragma unroll
    for (int k = 0; k < 16; k++) {
        a0 = fmaf(attk[k], (float)hv[k][0], a0);
        a1 = fmaf(attk[k], (float)hv[k][1], a1);
        a2 = fmaf(attk[k], (float)hv[k][2], a2);
        a3 = fmaf(attk[k], (float)hv[k][3], a3);
    }
    const float4 bv = *(const float4*)&bias[j * 4];
    float4 o;
    o.x = fmaxf(a0 + bv.x, 0.0f);
    o.y = fmaxf(a1 + bv.y, 0.0f);
    o.z = fmaxf(a2 + bv.z, 0.0f);
    o.w = fmaxf(a3 + bv.w, 0.0f);
    *(float4*)&out[(size_t)dst * 64 + j * 4] = o;    // coalesced 256B/row
}

extern "C" void kernel_launch(void* const* d_in, const int* in_sizes, int n_in,
                              void* d_out, int out_size, void* d_ws, size_t ws_size,
                              hipStream_t stream)
{
    const float* x        = (const float*)d_in[0];
    const int*   edge_col = (const int*)  d_in[2];
    const float* W1       = (const float*)d_in[3];
    const float* a1       = (const float*)d_in[4];
    const float* b1       = (const float*)d_in[5];
    const float* W2       = (const float*)d_in[6];
    const float* a2       = (const float*)d_in[7];
    const float* b2       = (const float*)d_in[8];
    const int n = in_sizes[0] / 128;     // 100000

    _Float16* h  = (_Float16*)d_ws;                  // n*64 fp16
    float* xm = (float*)(h + (size_t)n * 64);        // n*64 fp32
    float* s1 = xm + (size_t)n * 64;                 // n
    float* s2 = s1 + n;                              // n

    const int gemm_blocks = (n + 191) / 192;         // 192 rows/block
    const int agg_blocks  = (n + 31) / 32;           // 32 nodes/block

    // layer 1
    gemm_score_mfma<128><<<gemm_blocks, 256, 0, stream>>>(x, W1, a1, h, s1, s2, n);
    attn_agg<<<agg_blocks, 512, 0, stream>>>(h, s1, s2, edge_col, b1, xm, n);
    // layer 2
    gemm_score_mfma<64><<<gemm_blocks, 256, 0, stream>>>(xm, W2, a2, h, s1, s2, n);
    attn_agg<<<agg_blocks, 512, 0, stream>>>(h, s1, s2, edge_col, b2, (float*)d_out, n);
}

// Round 5
// 187.895 us; speedup vs baseline: 1.8114x; 1.0132x over previous
//
#include <hip/hip_runtime.h>

// 2-layer GAT forward, N nodes, K=16 neighbors (row-sorted, exactly 16/dst),
// feats 128 -> 64 -> 64, fp32 in/out.
//
// GEMM on matrix cores via fp16 MFMA, A-single / W-dual split:
//   h ~= f16(x)*W_h + f16(x)*W_l,  W_h = f16(W), W_l = f16(W - W_h)
// A-side error 2^-11 (RMS-attenuated ~3e-4 abs), W captured to ~2^-22.
// All intermediates (H1, xm, H2) stored fp16: halves gather traffic AND lets
// the layer-2 GEMM load its MFMA A-fragments directly with b128 (no repack).

typedef __attribute__((ext_vector_type(8))) _Float16 f16x8;
typedef __attribute__((ext_vector_type(4))) _Float16 f16x4;
typedef __attribute__((ext_vector_type(4))) float floatx4;

__device__ inline float ubitf(unsigned u) { union { unsigned u; float f; } v; v.u = u; return v.f; }
__device__ inline unsigned fbitu(float f) { union { float f; unsigned u; } v; v.f = f; return v.u; }

// ---- h = X @ W (fp16 MFMA) + fused s1 = h.a[:64], s2 = h.a[64:]; H fp16 ----
// 256 threads = 4 waves, 48 rows/wave (3 MFMA row-tiles), 192 rows/block.
// W (KDx64) -> dual-fp16 MFMA B-fragments in LDS (in-kernel preamble).
// B-frag f=(kt*4+nt)*64+lane holds B[k=kt*32+(lane>>4)*8+j][c=nt*16+(lane&15)]
template<int KD, bool A_F16>
__global__ __launch_bounds__(256, 2) void gemm_score_f16(
    const void* __restrict__ Xv, const float* __restrict__ W,
    const float* __restrict__ av, _Float16* __restrict__ H,
    float* __restrict__ s1, float* __restrict__ s2, int n)
{
    constexpr int NKT = KD / 32;
    constexpr int NF = NKT * 4 * 64;
    __shared__ f16x8 Bhi[NF];
    __shared__ f16x8 Blo[NF];
    const int tid = threadIdx.x;

    for (int f = tid; f < NF; f += 256) {
        const int ln = f & 63, ntk = f >> 6;
        const int kt = ntk >> 2, nt = ntk & 3;
        const int kbase = kt * 32 + (ln >> 4) * 8;
        const int ccol = nt * 16 + (ln & 15);
        f16x8 hh, ll;
#pragma unroll
        for (int j = 0; j < 8; j++) {
            const float w = W[(kbase + j) * 64 + ccol];
            const _Float16 wh = (_Float16)w;
            hh[j] = wh;
            ll[j] = (_Float16)(w - (float)wh);
        }
        Bhi[f] = hh; Blo[f] = ll;
    }
    __syncthreads();

    const int wave = tid >> 6, lane = tid & 63;
    const int quad = lane >> 4, l15 = lane & 15;
    const int r0 = blockIdx.x * 192 + wave * 48;

    float a1c[4], a2c[4];
#pragma unroll
    for (int nt = 0; nt < 4; nt++) {
        a1c[nt] = av[nt * 16 + l15];
        a2c[nt] = av[64 + nt * 16 + l15];
    }

    // ---- A fragments for the wave's 48 rows (all loads issued up front) ----
    f16x8 A[NKT][3];
    if constexpr (A_F16) {
        const _Float16* X = (const _Float16*)Xv;
#pragma unroll
        for (int rb = 0; rb < 3; rb++) {
            int ra = r0 + rb * 16 + l15; if (ra > n - 1) ra = n - 1;
            const _Float16* xp = &X[(size_t)ra * KD + quad * 8];
#pragma unroll
            for (int kt = 0; kt < NKT; kt++)
                A[kt][rb] = *(const f16x8*)(xp + kt * 32);
        }
    } else {
        const float* X = (const float*)Xv;
        float4 raw[NKT][3][2];
#pragma unroll
        for (int rb = 0; rb < 3; rb++) {
            int ra = r0 + rb * 16 + l15; if (ra > n - 1) ra = n - 1;
            const float* xp = &X[(size_t)ra * KD + quad * 8];
#pragma unroll
            for (int kt = 0; kt < NKT; kt++) {
                raw[kt][rb][0] = *(const float4*)(xp + kt * 32);
                raw[kt][rb][1] = *(const float4*)(xp + kt * 32 + 4);
            }
        }
#pragma unroll
        for (int kt = 0; kt < NKT; kt++)
#pragma unroll
            for (int rb = 0; rb < 3; rb++) {
                f16x8 a;
                a[0] = (_Float16)raw[kt][rb][0].x; a[1] = (_Float16)raw[kt][rb][0].y;
                a[2] = (_Float16)raw[kt][rb][0].z; a[3] = (_Float16)raw[kt][rb][0].w;
                a[4] = (_Float16)raw[kt][rb][1].x; a[5] = (_Float16)raw[kt][rb][1].y;
                a[6] = (_Float16)raw[kt][rb][1].z; a[7] = (_Float16)raw[kt][rb][1].w;
                A[kt][rb] = a;
            }
    }

    floatx4 acc[4][3];
#pragma unroll
    for (int nt = 0; nt < 4; nt++)
#pragma unroll
        for (int rb = 0; rb < 3; rb++) acc[nt][rb] = (floatx4){0, 0, 0, 0};

#pragma unroll
    for (int kt = 0; kt < NKT; kt++) {
#pragma unroll
        for (int nt = 0; nt < 4; nt++) {
            const f16x8 bh = Bhi[(kt * 4 + nt) * 64 + lane];
            const f16x8 bl = Blo[(kt * 4 + nt) * 64 + lane];
#pragma unroll
            for (int rb = 0; rb < 3; rb++) {
                acc[nt][rb] = __builtin_amdgcn_mfma_f32_16x16x32_f16(A[kt][rb], bh, acc[nt][rb], 0, 0, 0);
                acc[nt][rb] = __builtin_amdgcn_mfma_f32_16x16x32_f16(A[kt][rb], bl, acc[nt][rb], 0, 0, 0);
            }
        }
    }

    // ---- epilogue: C layout col=nt*16+l15, row=quad*4+reg ----
#pragma unroll
    for (int rb = 0; rb < 3; rb++) {
        float p1[4] = {0, 0, 0, 0}, p2[4] = {0, 0, 0, 0};
#pragma unroll
        for (int nt = 0; nt < 4; nt++) {
#pragma unroll
            for (int reg = 0; reg < 4; reg++) {
                const int r = r0 + rb * 16 + quad * 4 + reg;
                if (r < n) H[(size_t)r * 64 + nt * 16 + l15] = (_Float16)acc[nt][rb][reg];
                p1[reg] = fmaf(acc[nt][rb][reg], a1c[nt], p1[reg]);
                p2[reg] = fmaf(acc[nt][rb][reg], a2c[nt], p2[reg]);
            }
        }
#pragma unroll
        for (int m = 1; m < 16; m <<= 1) {
#pragma unroll
            for (int reg = 0; reg < 4; reg++) {
                p1[reg] += __shfl_xor(p1[reg], m, 64);
                p2[reg] += __shfl_xor(p2[reg], m, 64);
            }
        }
        if (l15 == 0) {
#pragma unroll
            for (int reg = 0; reg < 4; reg++) {
                const int r = r0 + rb * 16 + quad * 4 + reg;
                if (r < n) { s1[r] = p1[reg]; s2[r] = p2[reg]; }
            }
        }
    }
}

// ---- attention + aggregate: 4 nodes per wave, 16 lanes per node ------------
// lane = g*16+j; lane owns output feats j*4..j*4+3; gathers f16x4 (8B/lane)
// -> 512B of H per gather instruction. OT = _Float16 (->xm) or float (->out).
template<typename OT>
__global__ __launch_bounds__(512) void attn_agg(
    const _Float16* __restrict__ H, const float* __restrict__ s1,
    const float* __restrict__ s2, const int* __restrict__ col,
    const float* __restrict__ bias, OT* __restrict__ out, int n)
{
    const int lane = threadIdx.x & 63;
    const int wv = threadIdx.x >> 6;                 // 0..7
    const int j = lane & 15;
    const int dst = blockIdx.x * 32 + wv * 4 + (lane >> 4);
    if (dst >= n) return;

    const int c = col[dst * 16 + j];                 // coalesced 256B/wave
    float e = s1[dst] + s2[c];
    e = (e > 0.0f) ? e : 0.2f * e;                   // leaky_relu 0.2
    float m = e;
#pragma unroll
    for (int mk = 1; mk < 16; mk <<= 1) m = fmaxf(m, __shfl_xor(m, mk, 64));
    float p = __expf(e - m);
    float s = p;
#pragma unroll
    for (int mk = 1; mk < 16; mk <<= 1) s += __shfl_xor(s, mk, 64);
    const float att = p / s;

    // broadcast (src,att) of the group's 16 edges to all 16 lanes
    const int bbase = (lane & 48) << 2;
    int srck[16]; float attk[16];
#pragma unroll
    for (int k = 0; k < 16; k++) {
        const int bidx = bbase + (k << 2);
        srck[k] = __builtin_amdgcn_ds_bpermute(bidx, c);
        attk[k] = ubitf((unsigned)__builtin_amdgcn_ds_bpermute(bidx, (int)fbitu(att)));
    }
    f16x4 hv[16];
#pragma unroll
    for (int k = 0; k < 16; k++)
        hv[k] = *(const f16x4*)&H[(size_t)srck[k] * 64 + j * 4];

    float a0 = 0, a1 = 0, a2 = 0, a3 = 0;
#pragma unroll
    for (int k = 0; k < 16; k++) {
        a0 = fmaf(attk[k], (float)hv[k][0], a0);
        a1 = fmaf(attk[k], (float)hv[k][1], a1);
        a2 = fmaf(attk[k], (float)hv[k][2], a2);
        a3 = fmaf(attk[k], (float)hv[k][3], a3);
    }
    const float4 bv = *(const float4*)&bias[j * 4];
    const float o0 = fmaxf(a0 + bv.x, 0.0f);
    const float o1 = fmaxf(a1 + bv.y, 0.0f);
    const float o2 = fmaxf(a2 + bv.z, 0.0f);
    const float o3 = fmaxf(a3 + bv.w, 0.0f);
    if constexpr (sizeof(OT) == 2) {
        f16x4 o; o[0] = (_Float16)o0; o[1] = (_Float16)o1;
                 o[2] = (_Float16)o2; o[3] = (_Float16)o3;
        *(f16x4*)&out[(size_t)dst * 64 + j * 4] = o;
    } else {
        float4 o; o.x = o0; o.y = o1; o.z = o2; o.w = o3;
        *(float4*)&out[(size_t)dst * 64 + j * 4] = o;
    }
}

extern "C" void kernel_launch(void* const* d_in, const int* in_sizes, int n_in,
                              void* d_out, int out_size, void* d_ws, size_t ws_size,
                              hipStream_t stream)
{
    const float* x        = (const float*)d_in[0];
    const int*   edge_col = (const int*)  d_in[2];
    const float* W1       = (const float*)d_in[3];
    const float* a1       = (const float*)d_in[4];
    const float* b1       = (const float*)d_in[5];
    const float* W2       = (const float*)d_in[6];
    const float* a2       = (const float*)d_in[7];
    const float* b2       = (const float*)d_in[8];
    const int n = in_sizes[0] / 128;     // 100000

    _Float16* h  = (_Float16*)d_ws;                  // n*64 fp16
    _Float16* xm = h + (size_t)n * 64;               // n*64 fp16
    float* s1 = (float*)(xm + (size_t)n * 64);       // n
    float* s2 = s1 + n;                              // n

    const int gemm_blocks = (n + 191) / 192;
    const int agg_blocks  = (n + 31) / 32;

    // layer 1 (A from fp32 x, cvt to fp16)
    gemm_score_f16<128, false><<<gemm_blocks, 256, 0, stream>>>(x, W1, a1, h, s1, s2, n);
    attn_agg<_Float16><<<agg_blocks, 512, 0, stream>>>(h, s1, s2, edge_col, b1, xm, n);
    // layer 2 (A = fp16 xm, direct b128 fragment loads)
    gemm_score_f16<64, true><<<gemm_blocks, 256, 0, stream>>>(xm, W2, a2, h, s1, s2, n);
    attn_agg<float><<<agg_blocks, 512, 0, stream>>>(h, s1, s2, edge_col, b2, (float*)d_out, n);
}